// Round 2
// baseline (5307.327 us; speedup 1.0000x reference)
//
#include <hip/hip_runtime.h>
#include <cstdint>
#include <cstddef>

typedef unsigned int u32;
typedef unsigned short u16;

typedef __attribute__((ext_vector_type(8))) short s16x8;
typedef __attribute__((ext_vector_type(4))) float f32x4;

#define H 256
#define NT 32
#define LDW 264
#define GLDW 1032

#define MFMA(a, b, c) __builtin_amdgcn_mfma_f32_16x16x32_bf16((a), (b), (c), 0, 0, 0)

__device__ __forceinline__ u32 f2bf(float f) {
    union { float f; u32 u; } v; v.f = f;
    return (v.u + 0x7FFFu + ((v.u >> 16) & 1u)) >> 16;
}
__device__ __forceinline__ float bflo(u32 p) { union { u32 u; float f; } v; v.u = p << 16; return v.f; }
__device__ __forceinline__ float bfhi(u32 p) { union { u32 u; float f; } v; v.u = p & 0xFFFF0000u; return v.f; }

__device__ __forceinline__ float fexp2(float x) { return __builtin_amdgcn_exp2f(x); }
__device__ __forceinline__ float frcp(float x) { return __builtin_amdgcn_rcpf(x); }
__device__ __forceinline__ float fsigmoid(float x) { return frcp(1.0f + fexp2(-1.4426950408889634f * x)); }
__device__ __forceinline__ float ftanh(float x) { return 1.0f - 2.0f * frcp(1.0f + fexp2(2.8853900817779268f * x)); }

// Convert weights to bf16, fuse biases. Grid: 1024 x 256 covers 262144.
__global__ void prep_kernel(const float* Wih_l, const float* Whh_l, const float* bih_l, const float* bhh_l,
                            const float* Wih_r, const float* Whh_r, const float* bih_r, const float* bhh_r,
                            const float* Wenc, const float* benc,
                            u16* wihl, u16* whhl, u16* wihr, u16* whhr, u16* wencb,
                            float* bsl, float* bsr, float* bencf) {
    int i = blockIdx.x * 256 + threadIdx.x;
    if (i < 262144) {
        wihl[i] = (u16)f2bf(Wih_l[i]);
        whhl[i] = (u16)f2bf(Whh_l[i]);
        wihr[i] = (u16)f2bf(Wih_r[i]);
        whhr[i] = (u16)f2bf(Whh_r[i]);
    }
    if (i < 131072) wencb[i] = (u16)f2bf(Wenc[i]);
    if (i < 1024) { bsl[i] = bih_l[i] + bhh_l[i]; bsr[i] = bih_r[i] + bhh_r[i]; }
    if (i < 256) bencf[i] = benc[i];
}

// One level of the tree: each WG handles NT=32 nodes fully fused
// (left LSTM T steps, right LSTM T steps, encoder).
__launch_bounds__(256, 1)
__global__ void level_kernel(const float* __restrict__ node_init, u16* __restrict__ shadow,
                             const u16* __restrict__ wihl, const u16* __restrict__ whhl,
                             const u16* __restrict__ wihr, const u16* __restrict__ whhr,
                             const u16* __restrict__ wenc,
                             const float* __restrict__ bsl, const float* __restrict__ bsr,
                             const float* __restrict__ bencf,
                             float* __restrict__ dout,
                             int off, int coff, int n, int T, int is_leaf, int is_root) {
    __shared__ u16 x_lds[NT][LDW];
    __shared__ u16 h_lds[NT][LDW];
    __shared__ u16 el_lds[NT][LDW];
    __shared__ u16 gates_lds[NT][GLDW];

    const int tid = threadIdx.x;
    const int wv = tid >> 6;
    const int lane = tid & 63;
    const int lrow = lane & 15;
    const int quad = lane >> 4;
    const int nb = blockIdx.x * NT;

    float c_reg[32];

    for (int side = 0; side < 2; ++side) {
        const u16* Wih = side ? wihr : wihl;
        const u16* Whh = side ? whhr : whhl;
        const float* bsum = side ? bsr : bsl;

        for (int t = 0; t < T; ++t) {
            // ---- stage x tile into LDS (bf16) ----
            {
                const int row = tid >> 3;
                const int c0 = (tid & 7) * 32;
                int gn = nb + row; if (gn >= n) gn = n - 1;
                const bool own = is_leaf || (side == 0 ? (t == 4) : (t == 0));
                if (own) {
                    const float* src = node_init + (size_t)(off + gn) * H + c0;
#pragma unroll
                    for (int q = 0; q < 4; ++q) {
                        float4 f0 = *(const float4*)(src + q * 8);
                        float4 f1 = *(const float4*)(src + q * 8 + 4);
                        uint4 pk;
                        pk.x = f2bf(f0.x) | (f2bf(f0.y) << 16);
                        pk.y = f2bf(f0.z) | (f2bf(f0.w) << 16);
                        pk.z = f2bf(f1.x) | (f2bf(f1.y) << 16);
                        pk.w = f2bf(f1.z) | (f2bf(f1.w) << 16);
                        *(uint4*)&x_lds[row][c0 + q * 8] = pk;
                    }
                } else {
                    const int cidx = (side == 0) ? (3 - t) : (3 + t);
                    const u16* src = shadow + (size_t)(coff + gn * 8 + cidx) * H + c0;
#pragma unroll
                    for (int q = 0; q < 4; ++q) {
                        uint4 v = *(const uint4*)(src + q * 8);
                        *(uint4*)&x_lds[row][c0 + q * 8] = v;
                    }
                }
            }
            __syncthreads();

            // ---- GEMM: gates = x@Wih^T (+ h@Whh^T if t>0) + bias ----
            {
                s16x8 ax[2][8];
#pragma unroll
                for (int kc = 0; kc < 8; ++kc) {
                    ax[0][kc] = *(const s16x8*)&x_lds[lrow][kc * 32 + quad * 8];
                    ax[1][kc] = *(const s16x8*)&x_lds[16 + lrow][kc * 32 + quad * 8];
                }
                s16x8 ah[2][8];
                if (t > 0) {
#pragma unroll
                    for (int kc = 0; kc < 8; ++kc) {
                        ah[0][kc] = *(const s16x8*)&h_lds[lrow][kc * 32 + quad * 8];
                        ah[1][kc] = *(const s16x8*)&h_lds[16 + lrow][kc * 32 + quad * 8];
                    }
                }
                for (int ntg = 0; ntg < 4; ++ntg) {
                    f32x4 acc[4][2] = {};
                    const int g0 = wv * 256 + ntg * 64 + lrow;
#pragma unroll
                    for (int kc = 0; kc < 8; ++kc) {
#pragma unroll
                        for (int u = 0; u < 4; ++u) {
                            s16x8 b = *(const s16x8*)(Wih + (size_t)(g0 + u * 16) * H + kc * 32 + quad * 8);
                            acc[u][0] = MFMA(ax[0][kc], b, acc[u][0]);
                            acc[u][1] = MFMA(ax[1][kc], b, acc[u][1]);
                        }
                    }
                    if (t > 0) {
#pragma unroll
                        for (int kc = 0; kc < 8; ++kc) {
#pragma unroll
                            for (int u = 0; u < 4; ++u) {
                                s16x8 b = *(const s16x8*)(Whh + (size_t)(g0 + u * 16) * H + kc * 32 + quad * 8);
                                acc[u][0] = MFMA(ah[0][kc], b, acc[u][0]);
                                acc[u][1] = MFMA(ah[1][kc], b, acc[u][1]);
                            }
                        }
                    }
#pragma unroll
                    for (int u = 0; u < 4; ++u) {
                        const int g = g0 + u * 16;
                        const float bias = bsum[g];
#pragma unroll
                        for (int r = 0; r < 4; ++r) {
                            gates_lds[quad * 4 + r][g] = (u16)f2bf(acc[u][0][r] + bias);
                            gates_lds[16 + quad * 4 + r][g] = (u16)f2bf(acc[u][1][r] + bias);
                        }
                    }
                }
            }
            __syncthreads();

            // ---- elementwise LSTM cell update ----
            {
                const int node = tid >> 3;
                const int j0 = (tid & 7) * 32;
                const bool to_el = (side == 0) && (t == T - 1);
                u16* dst = to_el ? &el_lds[node][0] : &h_lds[node][0];
#pragma unroll
                for (int jj = 0; jj < 32; jj += 2) {
                    const int j = j0 + jj;
                    u32 pi = *(const u32*)&gates_lds[node][j];
                    u32 pf = *(const u32*)&gates_lds[node][256 + j];
                    u32 pg = *(const u32*)&gates_lds[node][512 + j];
                    u32 po = *(const u32*)&gates_lds[node][768 + j];
                    float i0 = fsigmoid(bflo(pi)), i1 = fsigmoid(bfhi(pi));
                    float f0 = fsigmoid(bflo(pf)), f1 = fsigmoid(bfhi(pf));
                    float g0 = ftanh(bflo(pg)),    g1 = ftanh(bfhi(pg));
                    float o0 = fsigmoid(bflo(po)), o1 = fsigmoid(bfhi(po));
                    float c0 = (t == 0) ? (i0 * g0) : (f0 * c_reg[jj] + i0 * g0);
                    float c1 = (t == 0) ? (i1 * g1) : (f1 * c_reg[jj + 1] + i1 * g1);
                    c_reg[jj] = c0; c_reg[jj + 1] = c1;
                    float h0 = o0 * ftanh(c0);
                    float h1 = o1 * ftanh(c1);
                    *(u32*)&dst[j] = f2bf(h0) | (f2bf(h1) << 16);
                }
            }
            __syncthreads();
        } // t
    } // side

    // ---- encoder: enc = tanh([el | er] @ Wenc^T + benc); er == h_lds ----
    {
        s16x8 ael[2][8], aer[2][8];
#pragma unroll
        for (int kc = 0; kc < 8; ++kc) {
            ael[0][kc] = *(const s16x8*)&el_lds[lrow][kc * 32 + quad * 8];
            ael[1][kc] = *(const s16x8*)&el_lds[16 + lrow][kc * 32 + quad * 8];
            aer[0][kc] = *(const s16x8*)&h_lds[lrow][kc * 32 + quad * 8];
            aer[1][kc] = *(const s16x8*)&h_lds[16 + lrow][kc * 32 + quad * 8];
        }
        f32x4 acc[4][2] = {};
#pragma unroll
        for (int kc = 0; kc < 8; ++kc) {
#pragma unroll
            for (int u = 0; u < 4; ++u) {
                const int cb = wv * 64 + u * 16 + lrow;
                s16x8 b0 = *(const s16x8*)(wenc + (size_t)cb * 512 + kc * 32 + quad * 8);
                acc[u][0] = MFMA(ael[0][kc], b0, acc[u][0]);
                acc[u][1] = MFMA(ael[1][kc], b0, acc[u][1]);
                s16x8 b1 = *(const s16x8*)(wenc + (size_t)cb * 512 + 256 + kc * 32 + quad * 8);
                acc[u][0] = MFMA(aer[0][kc], b1, acc[u][0]);
                acc[u][1] = MFMA(aer[1][kc], b1, acc[u][1]);
            }
        }
        // stage enc (fp32) into gates_lds space, then coalesced write-out
        float* encs = (float*)&gates_lds[0][0]; // stride 260 floats per row
#pragma unroll
        for (int u = 0; u < 4; ++u) {
            const int col = wv * 64 + u * 16 + lrow;
            const float bias = bencf[col];
#pragma unroll
            for (int r = 0; r < 4; ++r) {
                encs[(quad * 4 + r) * 260 + col] = ftanh(acc[u][0][r] + bias);
                encs[(16 + quad * 4 + r) * 260 + col] = ftanh(acc[u][1][r] + bias);
            }
        }
    }
    __syncthreads();

    // ---- write enc to shadow (bf16) and root output (fp32) ----
    {
        const int row = tid >> 3;
        const int c0 = (tid & 7) * 32;
        const int gn = nb + row;
        if (gn < n) {
            const float* encs = (const float*)&gates_lds[0][0];
            u16* dst = shadow + (size_t)(off + gn) * H + c0;
#pragma unroll
            for (int q = 0; q < 4; ++q) {
                float4 f0 = *(const float4*)&encs[row * 260 + c0 + q * 8];
                float4 f1 = *(const float4*)&encs[row * 260 + c0 + q * 8 + 4];
                uint4 pk;
                pk.x = f2bf(f0.x) | (f2bf(f0.y) << 16);
                pk.y = f2bf(f0.z) | (f2bf(f0.w) << 16);
                pk.z = f2bf(f1.x) | (f2bf(f1.y) << 16);
                pk.w = f2bf(f1.z) | (f2bf(f1.w) << 16);
                *(uint4*)(dst + q * 8) = pk;
            }
            if (is_root && gn == 0) {
#pragma unroll
                for (int q = 0; q < 32; ++q) dout[c0 + q] = encs[row * 260 + c0 + q];
            }
        }
    }
}

extern "C" void kernel_launch(void* const* d_in, const int* in_sizes, int n_in,
                              void* d_out, int out_size, void* d_ws, size_t ws_size,
                              hipStream_t stream) {
    (void)in_sizes; (void)n_in; (void)out_size; (void)ws_size;
    const float* node_init = (const float*)d_in[0];
    const float* Wih_l = (const float*)d_in[1];
    const float* Whh_l = (const float*)d_in[2];
    const float* bih_l = (const float*)d_in[3];
    const float* bhh_l = (const float*)d_in[4];
    const float* Wih_r = (const float*)d_in[5];
    const float* Whh_r = (const float*)d_in[6];
    const float* bih_r = (const float*)d_in[7];
    const float* bhh_r = (const float*)d_in[8];
    const float* Wenc  = (const float*)d_in[9];
    const float* benc  = (const float*)d_in[10];

    // workspace layout
    u16* shadow = (u16*)d_ws;                              // 299593*256 bf16 = 153.4 MB
    u16* wihl = shadow + (size_t)299593 * 256;
    u16* whhl = wihl + 262144;
    u16* wihr = whhl + 262144;
    u16* whhr = wihr + 262144;
    u16* wencb = whhr + 262144;                            // 131072
    float* bsl = (float*)(wencb + 131072);
    float* bsr = bsl + 1024;
    float* bencf = bsr + 1024;

    prep_kernel<<<dim3(1024), dim3(256), 0, stream>>>(
        Wih_l, Whh_l, bih_l, bhh_l, Wih_r, Whh_r, bih_r, bhh_r, Wenc, benc,
        wihl, whhl, wihr, whhr, wencb, bsl, bsr, bencf);

    static const int OFF[8] = {0, 1, 9, 73, 585, 4681, 37449, 299593};
    static const int SZ[7]  = {1, 8, 64, 512, 4096, 32768, 262144};

    for (int d = 6; d >= 0; --d) {
        const int n = SZ[d];
        const int T = (d == 6) ? 1 : 5;
        dim3 grid((n + NT - 1) / NT);
        level_kernel<<<grid, dim3(256), 0, stream>>>(
            node_init, shadow, wihl, whhl, wihr, whhr, wencb, bsl, bsr, bencf,
            (float*)d_out, OFF[d], (d < 6) ? OFF[d + 1] : 0, n, T,
            (d == 6) ? 1 : 0, (d == 0) ? 1 : 0);
    }
}